// Round 5
// baseline (228.243 us; speedup 1.0000x reference)
//
#include <hip/hip_runtime.h>

// B=4, S=2048, D=768, H=12, HD=64. I/O f32; internal bf16 MFMA.
// ws: wqkv_t [2304][768] | wout_t [768][768] | q_ws, k_ws [B,H,S,64] (bf16)
// d_out scratch: lower half Vt (bf16 [B,H,HD,S], TRUE s order), upper half x_bf16.
// attn output overwrites q_ws rows in place (block-local; race-free).
// Q is pre-scaled by SCALE*log2(e) at the QKV epilogue (softmax uses raw exp2).
#define BB 4
#define SS 2048
#define DD 768
#define HH 12
#define HDIM 64

using bf16_t = __bf16;
typedef __bf16 bf16x8 __attribute__((ext_vector_type(8)));
typedef __bf16 bf16x4 __attribute__((ext_vector_type(4)));
typedef __bf16 bf16x2 __attribute__((ext_vector_type(2)));
typedef float f32x4 __attribute__((ext_vector_type(4)));
typedef float f32x16 __attribute__((ext_vector_type(16)));
typedef unsigned int u32;
typedef unsigned int u32x4 __attribute__((ext_vector_type(4)));

// async global->LDS 16B per lane; LDS dst is wave-uniform base + lane*16
static __device__ __forceinline__ void cp16(void* lds, const void* g) {
  __builtin_amdgcn_global_load_lds(
      (const __attribute__((address_space(1))) u32*)g,
      (__attribute__((address_space(3))) u32*)lds, 16, 0, 0);
}

// ---------------------------------------------------------------------------
// x f32 [M,K] -> bf16 (contiguous copy+convert)
// ---------------------------------------------------------------------------
__global__ void cvt_x(const float* __restrict__ in, bf16_t* __restrict__ out) {
  const size_t i = ((size_t)blockIdx.x * 256 + threadIdx.x) * 8;
  f32x4 f0 = *(const f32x4*)(in + i);
  f32x4 f1 = *(const f32x4*)(in + i + 4);
  bf16x8 v;
#pragma unroll
  for (int j = 0; j < 4; j++) { v[j] = (bf16_t)f0[j]; v[4 + j] = (bf16_t)f1[j]; }
  *(bf16x8*)(out + i) = v;
}

// ---------------------------------------------------------------------------
// Weight transpose + f32->bf16: in [K][N] f32 -> out [N][K] bf16
// ---------------------------------------------------------------------------
__global__ void wt_transpose(const float* __restrict__ in, bf16_t* __restrict__ out,
                             int K, int N) {
  __shared__ bf16_t tile[64][65];
  const int n0 = blockIdx.x * 64, k0 = blockIdx.y * 64;
  const int t = threadIdx.x;       // 256 threads
  const int r = t >> 2;            // 0..63
  const int c0 = (t & 3) * 16;     // 0,16,32,48
  const float* src = in + (size_t)(k0 + r) * N + n0 + c0;
#pragma unroll
  for (int q = 0; q < 4; q++) {
    f32x4 f = *(const f32x4*)(src + q * 4);
#pragma unroll
    for (int j = 0; j < 4; j++) tile[r][c0 + q * 4 + j] = (bf16_t)f[j];
  }
  __syncthreads();
  bf16x8 o0, o1;
#pragma unroll
  for (int j = 0; j < 8; j++) { o0[j] = tile[c0 + j][r]; o1[j] = tile[c0 + 8 + j][r]; }
  *(bf16x8*)(out + (size_t)(n0 + r) * K + k0 + c0) = o0;
  *(bf16x8*)(out + (size_t)(n0 + r) * K + k0 + c0 + 8) = o1;
}

// ---------------------------------------------------------------------------
// GEMM: C[M,N] = A[M,K] @ Bt[N,K]^T, all-bf16, fp32 MFMA accum. 128x128 tile,
// BK=64, 4 waves. global_load_lds staging into DOUBLE-BUFFERED LDS:
// one barrier per K-step; prefetch for step kt+1 issued right after the
// barrier so its DMA has the whole step to land (round-1: exposed DMA drain
// was the bottleneck; round-3 confirmed gemm left the top-5).
// XCD-chunked bijective swizzle keeps A m-band + B panel L2-resident.
// MODE 0: A = x_bf16 [M,K]; epi scatters Q (pre-scaled by SCALE*log2e), K ->
//         [B,H,S,HD], V -> Vt [B,H,HD,S] in TRUE s order (attn P is now
//         true-s-ordered in registers, so no V permutation needed).
// MODE 1: A = bf16 head-interleaved [B,H,S,HD]; epi adds f32 bias, writes f32.
// ---------------------------------------------------------------------------
template <int MODE>
__global__ __launch_bounds__(256, 2)
void gemm_bt(const bf16_t* __restrict__ A, const bf16_t* __restrict__ Bt,
             int M, int N, int K,
             bf16_t* __restrict__ q_out, bf16_t* __restrict__ k_out,
             bf16_t* __restrict__ vt_out,
             float* __restrict__ Cout, const float* __restrict__ bias) {
  __shared__ bf16_t As[2][128][64];
  __shared__ bf16_t Bs[2][128][64];
  const int t = threadIdx.x;
  const int lane = t & 63, wave = t >> 6;
  const int l15 = lane & 15, quad = lane >> 4;
  const int wm = (wave >> 1) * 64, wn = (wave & 1) * 64;

  const int nx = gridDim.x;
  const int L = blockIdx.y * nx + blockIdx.x;
  const int chunk = (nx * gridDim.y) >> 3;
  const int v = (L & 7) * chunk + (L >> 3);
  const int m0 = (v / nx) * 128, n0 = (v % nx) * 128;

  const int srow = lane >> 3;
  const int schunk = ((lane & 7) ^ srow) * 8;
  const int rsw = l15 & 7;

  f32x4 acc[4][4];
#pragma unroll
  for (int i = 0; i < 4; i++)
#pragma unroll
    for (int j = 0; j < 4; j++) acc[i][j] = (f32x4){0.f, 0.f, 0.f, 0.f};

  auto stage = [&](int k0, int buf) {
#pragma unroll
    for (int p = 0; p < 4; p++) {
      const int row = wave * 32 + p * 8 + srow;
      const bf16_t* asrc;
      if (MODE == 0) {
        asrc = A + (size_t)(m0 + row) * K + k0 + schunk;
      } else {
        const int mm = m0 + row, b = mm >> 11, s = mm & 2047, h = k0 >> 6;
        asrc = A + (((size_t)(b * HH + h)) * SS + s) * HDIM + schunk;
      }
      cp16(&As[buf][wave * 32 + p * 8][0], asrc);
      cp16(&Bs[buf][wave * 32 + p * 8][0],
           Bt + (size_t)(n0 + row) * K + k0 + schunk);
    }
  };

  const int NT = K / 64;
  stage(0, 0);

  for (int kt = 0; kt < NT; kt++) {
    const int buf = kt & 1;
    __syncthreads();
    if (kt + 1 < NT) stage((kt + 1) * 64, buf ^ 1);
#pragma unroll
    for (int kk = 0; kk < 2; kk++) {
      bf16x8 af[4], bfr[4];
#pragma unroll
      for (int i = 0; i < 4; i++)
        af[i] = *(const bf16x8*)&As[buf][wm + i * 16 + l15][((kk * 4 + quad) ^ rsw) * 8];
#pragma unroll
      for (int j = 0; j < 4; j++)
        bfr[j] = *(const bf16x8*)&Bs[buf][wn + j * 16 + l15][((kk * 4 + quad) ^ rsw) * 8];
#pragma unroll
      for (int i = 0; i < 4; i++)
#pragma unroll
        for (int j = 0; j < 4; j++)
          acc[i][j] = __builtin_amdgcn_mfma_f32_16x16x32_bf16(af[i], bfr[j], acc[i][j], 0, 0, 0);
    }
  }

  // Epilogue. C/D layout: row = quad*4 + reg, col = l15.
  const float QSCALE = 0.125f * 1.44269504088896340736f;  // SCALE * log2(e)
#pragma unroll
  for (int i = 0; i < 4; i++) {
    const int mbase = m0 + wm + i * 16 + quad * 4;
#pragma unroll
    for (int j = 0; j < 4; j++) {
      const int n = n0 + wn + j * 16 + l15;
#pragma unroll
      for (int r = 0; r < 4; r++) {
        const float v = acc[i][j][r];
        const int mm = mbase + r;
        if (MODE == 0) {
          const int sel = n / DD;          // 0:Q 1:K 2:V
          const int rem = n - sel * DD;
          const int h = rem >> 6, d = rem & 63;
          const int b = mm >> 11, s = mm & 2047;
          if (sel == 2) {
            vt_out[((size_t)(b * HH + h) * HDIM + d) * SS + s] = (bf16_t)v;
          } else {
            const size_t idx = (((size_t)(b * HH + h)) * SS + s) * HDIM + d;
            if (sel == 0) q_out[idx] = (bf16_t)(v * QSCALE);
            else k_out[idx] = (bf16_t)v;
          }
        } else {
          Cout[(size_t)mm * N + n] = v + bias[n];
        }
      }
    }
  }
}

// ---------------------------------------------------------------------------
// Flash attention, streaming softmax, 32x32 MFMA + in-register P (T12).
// Block = 128 Q rows x one (b,h); 4 waves, 32 q-rows/wave.
//
// QK^T computed SWAPPED: S^T[k][q] = mfma_32x32x16(K-frag, Q-frag), so the
// C/D layout (col=lane&31, row=(r&3)+8*(r>>2)+4*hi) puts q on lane&31 —
// each lane owns 32 P-values of ITS q-row: k = 8g + 4*hi + m (g=r>>2, m=r&3).
//
// P-frag assembly (FIXED this round — round-4 had the operands backwards):
// w[g][i] packs k = 8g+4hi+{2i,2i+1}. pa[kk] needs elem j = P[q][kk*16+hi*8+j]:
//   hi=0 lane: j=0..3 own w[2sub][.],      j=4..7 partner(+32) w[2sub][.]
//   hi=1 lane: j=0..3 partner(-32) w[2sub+1][.], j=4..7 own w[2sub+1][.]
// v_permlane32_swap_b32 A,B swaps A.lanes[32:63] <-> B.lanes[0:31], so with
// A = w[2sub][i], B = w[2sub+1][i]:
//   lanes 0-31:  A = own w[2sub] (kept), B = partner's w[2sub]
//   lanes 32-63: A = partner's w[2sub+1], B = own w[2sub+1] (kept)
// => frag {A0,A1,B0,B1} is correct for BOTH halves.
//
// This deletes the Ps LDS round-trip (round-3: LDS pipe ~73% busy, chain
// stall-bound at MfmaUtil 30%). P is in TRUE s order -> Vt unpermuted.
// One barrier per KV-tile; prefetch issued right after it. XCD swizzle:
// 96 blocks/XCD = 6 whole heads (K+V L2-resident; FETCH 18.5MB confirmed).
// ---------------------------------------------------------------------------
__global__ __launch_bounds__(256, 3)
void attn_kernel(bf16_t* __restrict__ Qio, const bf16_t* __restrict__ Kg,
                 const bf16_t* __restrict__ Vt) {
  __shared__ bf16_t Ks[2][64][64];   // [buf][s_k][d]
  __shared__ bf16_t Vts[2][64][64];  // [buf][d][s]  (true s order)
  __shared__ float lsum[128];
  const int t = threadIdx.x;
  const int lane = t & 63, wave = t >> 6;
  const int l31 = lane & 31, hi = lane >> 5;

  // bijective XCD-aware remap: linear id -> contiguous chunk per XCD
  const int L = blockIdx.y * gridDim.x + blockIdx.x;        // 0..767
  const int v = (L & 7) * ((16 * BB * HH) / 8) + (L >> 3);  // 96 blocks/XCD
  const int bh = v >> 4;
  const int q0 = (v & 15) * 128;

  const size_t base = (size_t)bh * SS * HDIM;   // Q,K: [bh][s][d]
  const size_t baset = (size_t)bh * HDIM * SS;  // Vt:  [bh][d][s]
  const int wq = wave * 32;
  const int srow = lane >> 3;                   // 0..7
  const int schunk = ((lane & 7) ^ srow) * 8;   // element offset, swizzled
  const int rsw = l31 & 7;

  // Q fragments (one-time, B-operand): qf[kd] = Q[q0+wq+l31][kd*16+hi*8 ..+7]
  bf16x8 qf[4];
#pragma unroll
  for (int kd = 0; kd < 4; kd++)
    qf[kd] = *(const bf16x8*)(Qio + base + (size_t)(q0 + wq + l31) * HDIM +
                              kd * 16 + hi * 8);

  float l_lane = 0.f;
  f32x16 o_acc[2];
#pragma unroll
  for (int dt = 0; dt < 2; dt++)
#pragma unroll
    for (int r = 0; r < 16; r++) o_acc[dt][r] = 0.f;

  // stage one 64-tile: each wave 16 rows of K and V (2 x 8-row DMA each)
  auto stage = [&](int k0, int buf) {
#pragma unroll
    for (int p = 0; p < 2; p++) {
      const int row = wave * 16 + p * 8 + srow;
      cp16(&Ks[buf][wave * 16 + p * 8][0],
           Kg + base + (size_t)(k0 + row) * HDIM + schunk);
      cp16(&Vts[buf][wave * 16 + p * 8][0],
           Vt + baset + (size_t)row * SS + k0 + schunk);
    }
  };

  stage(0, 0);

  for (int it = 0; it < SS / 64; it++) {
    const int buf = it & 1;
    // drains stage(it) DMA (issued a full iteration ago) and fences prior
    // reads of buf^1 before the prefetch overwrites it.
    __syncthreads();
    if (it + 1 < SS / 64) stage((it + 1) * 64, buf ^ 1);

    // S^T = K @ Q^T  (swapped; logits pre-scaled by SCALE*log2e via Q)
    f32x16 sT[2];
#pragma unroll
    for (int ct = 0; ct < 2; ct++)
#pragma unroll
      for (int r = 0; r < 16; r++) sT[ct][r] = 0.f;
    __builtin_amdgcn_s_setprio(1);
#pragma unroll
    for (int ct = 0; ct < 2; ct++)
#pragma unroll
      for (int kd = 0; kd < 4; kd++) {
        bf16x8 kf = *(const bf16x8*)&Ks[buf][ct * 32 + l31][((2 * kd + hi) ^ rsw) * 8];
        sT[ct] = __builtin_amdgcn_mfma_f32_32x32x16_bf16(kf, qf[kd], sT[ct], 0, 0, 0);
      }
    __builtin_amdgcn_s_setprio(0);

    // P = exp2(S^T): lane holds P[q=l31][k = ct*32 + (r&3)+8*(r>>2)+4*hi].
    // cvt_pk into w[g][i] (k = 8g+4hi+{2i,2i+1}); permlane32_swap with
    // A = w[2sub][i], B = w[2sub+1][i]; frag = {A0,A1,B0,B1}.
    bf16x8 pa[4];
#pragma unroll
    for (int ct = 0; ct < 2; ct++) {
      float p[16];
#pragma unroll
      for (int r = 0; r < 16; r++) p[r] = __builtin_amdgcn_exp2f(sT[ct][r]);
#pragma unroll
      for (int r = 0; r < 16; r += 4)
        l_lane += (p[r] + p[r + 1]) + (p[r + 2] + p[r + 3]);
      u32 w[4][2];
#pragma unroll
      for (int g = 0; g < 4; g++)
#pragma unroll
        for (int i = 0; i < 2; i++) {
          bf16x2 pk = {(bf16_t)p[4 * g + 2 * i], (bf16_t)p[4 * g + 2 * i + 1]};
          w[g][i] = *(u32*)&pk;
        }
#pragma unroll
      for (int sub = 0; sub < 2; sub++) {
        u32 a0 = w[2 * sub][0], b0 = w[2 * sub + 1][0];
        u32 a1 = w[2 * sub][1], b1 = w[2 * sub + 1][1];
        asm volatile("v_permlane32_swap_b32 %0, %1" : "+v"(a0), "+v"(b0));
        asm volatile("v_permlane32_swap_b32 %0, %1" : "+v"(a1), "+v"(b1));
        u32x4 fr = {a0, a1, b0, b1};
        pa[ct * 2 + sub] = *(bf16x8*)&fr;
      }
    }

    // O += P @ V  (A = pa from registers; B = V rows from LDS, true s order)
    __builtin_amdgcn_s_setprio(1);
#pragma unroll
    for (int kk = 0; kk < 4; kk++)
#pragma unroll
      for (int dt = 0; dt < 2; dt++) {
        bf16x8 vf = *(const bf16x8*)&Vts[buf][dt * 32 + l31][((2 * kk + hi) ^ rsw) * 8];
        o_acc[dt] = __builtin_amdgcn_mfma_f32_32x32x16_bf16(pa[kk], vf, o_acc[dt], 0, 0, 0);
      }
    __builtin_amdgcn_s_setprio(0);
  }

  // l: lane-local sum covers k-parity == hi; partner (^32) has the rest.
  const float lf = l_lane + __shfl_xor(l_lane, 32);
  lsum[wq + l31] = lf;  // both halves write the same value; own-wave region
  // O write: col = d = dt*32+l31, row = q = (r&3)+8*(r>>2)+4*hi (+wq).
#pragma unroll
  for (int r = 0; r < 16; r++) {
    const int q = wq + (r & 3) + 8 * (r >> 2) + 4 * hi;
    const float inv = 1.0f / lsum[q];
#pragma unroll
    for (int dt = 0; dt < 2; dt++) {
      const int d = dt * 32 + l31;
      Qio[base + (size_t)(q0 + q) * HDIM + d] = (bf16_t)(o_acc[dt][r] * inv);
    }
  }
}

// ---------------------------------------------------------------------------
extern "C" void kernel_launch(void* const* d_in, const int* in_sizes, int n_in,
                              void* d_out, int out_size, void* d_ws, size_t ws_size,
                              hipStream_t stream) {
  const float* x = (const float*)d_in[0];      // [B,S,D] f32
  const float* w_qkv = (const float*)d_in[1];  // [D, 3D] f32
  const float* w_out = (const float*)d_in[2];  // [D, D] f32
  const float* b_out = (const float*)d_in[3];  // [D] f32
  float* out = (float*)d_out;                  // [B,S,D] f32

  char* ws = (char*)d_ws;
  bf16_t* wqkv_t = (bf16_t*)ws; ws += (size_t)3 * DD * DD * 2;          // [3D][D]
  bf16_t* wout_t = (bf16_t*)ws; ws += (size_t)DD * DD * 2;              // [D][D]
  bf16_t* q_ws = (bf16_t*)ws;   ws += (size_t)BB * HH * SS * HDIM * 2;  // [B,H,S,HD]
  bf16_t* k_ws = (bf16_t*)ws;                                           // [B,H,S,HD]
  bf16_t* vt_sc = (bf16_t*)d_out;                       // d_out lower half: Vt
  bf16_t* xb = (bf16_t*)d_out + (size_t)BB * SS * DD;   // d_out upper half: x_bf16

  cvt_x<<<(BB * SS * DD) / (256 * 8), 256, 0, stream>>>(x, xb);
  wt_transpose<<<dim3(3 * DD / 64, DD / 64), 256, 0, stream>>>(w_qkv, wqkv_t, DD, 3 * DD);
  wt_transpose<<<dim3(DD / 64, DD / 64), 256, 0, stream>>>(w_out, wout_t, DD, DD);
  gemm_bt<0><<<dim3(3 * DD / 128, BB * SS / 128), 256, 0, stream>>>(
      xb, wqkv_t, BB * SS, 3 * DD, DD, q_ws, k_ws, vt_sc, nullptr, nullptr);
  attn_kernel<<<dim3(SS / 128, BB * HH), 256, 0, stream>>>(q_ws, k_ws, vt_sc);
  gemm_bt<1><<<dim3(DD / 128, BB * SS / 128), 256, 0, stream>>>(
      q_ws, wout_t, BB * SS, DD, DD, nullptr, nullptr, nullptr, out, b_out);
}